// Round 2
// baseline (2967.677 us; speedup 1.0000x reference)
//
#include <hip/hip_runtime.h>
#include <math.h>

// Problem constants (fixed by reference)
constexpr int BATCH = 256;
constexpr int NMEM  = 100000;
constexpr int CDIM  = 511;
constexpr int DDIM  = 512;
constexpr int TOT   = 640;   // 2*64 + 512
constexpr int KTOP  = 64;

// ---------------------------------------------------------------------------
// K1: tau[b,n] = sum_k c[b,k] * memc[n,k]   (256 x 100000, K=511)
// 64x64 tile, 256 threads, 4x4 micro-tile, Kc=16 LDS staging. fp32.
// ---------------------------------------------------------------------------
__global__ __launch_bounds__(256) void tau_gemm(const float* __restrict__ cc,
                                                const float* __restrict__ memc,
                                                float* __restrict__ tau) {
    __shared__ float As[16][64];  // [k][b]
    __shared__ float Bs[16][64];  // [k][n]
    int bt = blockIdx.x & 3;       // 4 b-tiles
    int nt = blockIdx.x >> 2;      // 1563 n-tiles
    int b0 = bt * 64, n0 = nt * 64;
    int t  = threadIdx.x;
    int ti = t & 15, tj = t >> 4;

    float acc[4][4];
#pragma unroll
    for (int i = 0; i < 4; i++)
#pragma unroll
        for (int j = 0; j < 4; j++) acc[i][j] = 0.f;

    for (int k0 = 0; k0 < CDIM; k0 += 16) {
#pragma unroll
        for (int r = 0; r < 4; r++) {
            int idx = t + r * 256;          // 0..1023
            int row = idx >> 4, kk = idx & 15;
            int k = k0 + kk;
            As[kk][row] = (k < CDIM) ? cc[(size_t)(b0 + row) * CDIM + k] : 0.f;
            int n = n0 + row;
            Bs[kk][row] = (k < CDIM && n < NMEM) ? memc[(size_t)n * CDIM + k] : 0.f;
        }
        __syncthreads();
#pragma unroll
        for (int kk = 0; kk < 16; kk++) {
            float av[4], bv[4];
            *(float4*)av = *(const float4*)&As[kk][ti * 4];
            *(float4*)bv = *(const float4*)&Bs[kk][tj * 4];
#pragma unroll
            for (int i = 0; i < 4; i++)
#pragma unroll
                for (int j = 0; j < 4; j++)
                    acc[i][j] = fmaf(av[i], bv[j], acc[i][j]);
        }
        __syncthreads();
    }
#pragma unroll
    for (int i = 0; i < 4; i++) {
        int rowb = b0 + ti * 4 + i;
#pragma unroll
        for (int j = 0; j < 4; j++) {
            int n = n0 + tj * 4 + j;
            if (n < NMEM) tau[(size_t)rowb * NMEM + n] = acc[i][j];
        }
    }
}

// ---------------------------------------------------------------------------
// K2: per-row top-64 (desc value, tie -> lower index), then fused gather.
// 12-bit radix histogram (1/8-octave bins) -> ~70-250 candidates -> 64x
// single-wave shuffle argmax (exact tie-break) -> gather memc rows.
// ---------------------------------------------------------------------------
constexpr int CAND_CAP = 2048;
constexpr int NBINS    = 4096;

__device__ inline unsigned mono_map(float f) {
    unsigned u = __float_as_uint(f);
    return u ^ ((u >> 31) ? 0xFFFFFFFFu : 0x80000000u);
}

__global__ __launch_bounds__(256) void topk_gather(const float* __restrict__ tau,
                                                   const float* __restrict__ memc,
                                                   float* __restrict__ mems) {
    int row = blockIdx.x;
    const float* tr = tau + (size_t)row * NMEM;
    __shared__ int   hist[NBINS];
    __shared__ int   segsum[256];
    __shared__ int   cnt;
    __shared__ int   cut_s;
    __shared__ float cv[CAND_CAP];
    __shared__ int   ci[CAND_CAP];
    __shared__ int   sel[KTOP];
    int t = threadIdx.x;

    for (int i = t; i < NBINS; i += 256) hist[i] = 0;
    if (t == 0) cnt = 0;
    __syncthreads();

    for (int n = t; n < NMEM; n += 256)
        atomicAdd(&hist[mono_map(tr[n]) >> 20], 1);
    __syncthreads();

    {   // segment sums (16 bins per thread)
        int s = 0, base = t * 16;
#pragma unroll
        for (int i = 0; i < 16; i++) s += hist[base + i];
        segsum[t] = s;
    }
    __syncthreads();
    if (t == 0) {
        int acc = 0, cut = 0;
        for (int s = 255; s >= 0; s--) {
            if (acc + segsum[s] >= KTOP) {
                int base = s * 16;
                for (int bb = 15; bb >= 0; bb--) {
                    acc += hist[base + bb];
                    if (acc >= KTOP) { cut = base + bb; break; }
                }
                break;
            }
            acc += segsum[s];
        }
        cut_s = cut;
    }
    __syncthreads();
    unsigned cut = (unsigned)cut_s;
    for (int n = t; n < NMEM; n += 256) {
        float v = tr[n];
        if ((mono_map(v) >> 20) >= cut) {
            int p = atomicAdd(&cnt, 1);
            if (p < CAND_CAP) { cv[p] = v; ci[p] = n; }
        }
    }
    __syncthreads();
    int m = cnt < CAND_CAP ? cnt : CAND_CAP;   // >= KTOP by cut construction

    if (t < 64) {
        // single-wave extraction: no barriers, shuffle butterfly w/ tie-break
        for (int j = 0; j < KTOP; j++) {
            float bv = -INFINITY;
            int   bi = 0x7FFFFFFF, bp = -1;
            for (int p = t; p < m; p += 64) {
                float v = cv[p]; int ii = ci[p];
                if (v > bv || (v == bv && ii < bi)) { bv = v; bi = ii; bp = p; }
            }
            float wv = bv; int wi = bi;
#pragma unroll
            for (int o = 1; o < 64; o <<= 1) {
                float ov = __shfl_xor(wv, o, 64);
                int   oi = __shfl_xor(wi, o, 64);
                if (ov > wv || (ov == wv && oi < wi)) { wv = ov; wi = oi; }
            }
            if (t == 0) {
                sel[j] = wi;
                mems[((size_t)row * KTOP + j) * DDIM] = wv;   // delta
            }
            if (bp >= 0 && bi == wi) cv[bp] = -INFINITY;      // owner clears
        }
    }
    __syncthreads();
    // gather memc rows
    for (int j = 0; j < KTOP; j++) {
        int src = sel[j];
        for (int col = t; col < CDIM; col += 256)
            mems[((size_t)row * KTOP + j) * DDIM + 1 + col] = memc[(size_t)src * CDIM + col];
    }
}

// ---------------------------------------------------------------------------
// K3: batched GEMM  Y[b] (16 rows) = X[b](16x512) @ W(512xNo) + bias [opt relu]
// grid = BATCH*4 blocks (16 rows each), 256 threads, 1 output col/thread/chunk.
// ---------------------------------------------------------------------------
__global__ __launch_bounds__(256) void gemm_rows16(const float* __restrict__ X,
                                                   const float* __restrict__ W,
                                                   const float* __restrict__ bias,
                                                   float* __restrict__ Y,
                                                   int No, int do_relu) {
    int bx = blockIdx.x;
    int b  = bx >> 2;
    int r0 = (bx & 3) * 16;
    const float* Xb = X + ((size_t)b * 64 + r0) * DDIM;
    float*       Yb = Y + ((size_t)b * 64 + r0) * (size_t)No;
    int t = threadIdx.x;

    for (int c0 = t; c0 < No; c0 += 256) {
        float acc[16];
#pragma unroll
        for (int i = 0; i < 16; i++) acc[i] = 0.f;
        const float* Wc = W + c0;
        for (int k = 0; k < DDIM; k += 4) {
            float w0 = Wc[(size_t)(k + 0) * No];
            float w1 = Wc[(size_t)(k + 1) * No];
            float w2 = Wc[(size_t)(k + 2) * No];
            float w3 = Wc[(size_t)(k + 3) * No];
#pragma unroll
            for (int i = 0; i < 16; i++) {
                float4 x4 = *(const float4*)(Xb + i * DDIM + k);
                acc[i] = fmaf(x4.w, w3, fmaf(x4.z, w2, fmaf(x4.y, w1, fmaf(x4.x, w0, acc[i]))));
            }
        }
        float bb = bias[c0];
#pragma unroll
        for (int i = 0; i < 16; i++) {
            float v = acc[i] + bb;
            if (do_relu) v = fmaxf(v, 0.f);
            Yb[(size_t)i * No + c0] = v;
        }
    }
}

// ---------------------------------------------------------------------------
// K4: attention per batch.
// ---------------------------------------------------------------------------
__global__ __launch_bounds__(256) void attn(const float* __restrict__ qkv,
                                            float* __restrict__ att) {
    __shared__ float smem[64 * 65 * 2];   // qs | ks, later reused as vs
    __shared__ float wsm[64][64];
    float (*qs)[65]  = (float(*)[65])smem;
    float (*ks)[65]  = (float(*)[65])(smem + 64 * 65);
    float (*vs)[128] = (float(*)[128])smem;

    int b = blockIdx.x, t = threadIdx.x;
    const float* Qb = qkv + (size_t)b * 64 * TOT;

    for (int idx = t; idx < 64 * 64; idx += 256) {
        int i = idx >> 6, d = idx & 63;
        qs[i][d] = Qb[(size_t)i * TOT + d];
        ks[i][d] = Qb[(size_t)i * TOT + 64 + d];
    }
    __syncthreads();
    {
        int i  = t >> 2;
        int jb = (t & 3) * 16;
#pragma unroll
        for (int jj = 0; jj < 16; jj++) {
            int j = jb + jj;
            float s = 0.f;
#pragma unroll 8
            for (int d = 0; d < 64; d++) s = fmaf(qs[i][d], ks[j][d], s);
            wsm[i][j] = s * 0.125f;   // 64^{-1/2}
        }
    }
    __syncthreads();
    if (t < 64) {
        float mx = -INFINITY;
        for (int j = 0; j < 64; j++) mx = fmaxf(mx, wsm[t][j]);
        float sum = 0.f;
        for (int j = 0; j < 64; j++) { float e = expf(wsm[t][j] - mx); wsm[t][j] = e; sum += e; }
        float inv = 1.f / sum;
        for (int j = 0; j < 64; j++) wsm[t][j] *= inv;
    }
    __syncthreads();
    for (int ch = 0; ch < 4; ch++) {
        for (int idx = t; idx < 64 * 128; idx += 256) {
            int j = idx >> 7, d = idx & 127;
            vs[j][d] = Qb[(size_t)j * TOT + 128 + ch * 128 + d];
        }
        __syncthreads();
        int d  = t & 127;
        int i0 = (t >> 7) * 32;
        for (int i = i0; i < i0 + 32; i++) {
            float s = 0.f;
#pragma unroll 8
            for (int j = 0; j < 64; j++) s = fmaf(wsm[i][j], vs[j][d], s);
            att[((size_t)b * 64 + i) * DDIM + ch * 128 + d] = s;
        }
        __syncthreads();
    }
}

// ---------------------------------------------------------------------------
// K5: Y[row] = LN(X[row] (+ Res[row])) * g + b    one wave per row.
// ---------------------------------------------------------------------------
__global__ __launch_bounds__(256) void res_ln(const float* __restrict__ X,
                                              const float* __restrict__ Res,
                                              const float* __restrict__ g,
                                              const float* __restrict__ bta,
                                              float* __restrict__ Y,
                                              int width, int nrows) {
    int wave = threadIdx.x >> 6;
    int lane = threadIdx.x & 63;
    int row  = blockIdx.x * 4 + wave;
    if (row >= nrows) return;
    const float* xr = X + (size_t)row * width;
    const float* rr = Res ? Res + (size_t)row * width : nullptr;
    float vals[12];
    int per = width >> 6;   // 8 (512) or 10 (640)
    float sum = 0.f, ssq = 0.f;
    for (int e = 0; e < per; e++) {
        int col = lane + e * 64;
        float v = xr[col];
        if (rr) v += rr[col];
        vals[e] = v; sum += v; ssq = fmaf(v, v, ssq);
    }
    for (int o = 32; o > 0; o >>= 1) {
        sum += __shfl_down(sum, o, 64);
        ssq += __shfl_down(ssq, o, 64);
    }
    sum = __shfl(sum, 0, 64);
    ssq = __shfl(ssq, 0, 64);
    float mu  = sum / width;
    float var = ssq / width - mu * mu;
    float rs  = rsqrtf(var + 1e-5f);
    float* yr = Y + (size_t)row * width;
    for (int e = 0; e < per; e++) {
        int col = lane + e * 64;
        yr[col] = (vals[e] - mu) * rs * g[col] + bta[col];
    }
}

// ---------------------------------------------------------------------------
extern "C" void kernel_launch(void* const* d_in, const int* in_sizes, int n_in,
                              void* d_out, int out_size, void* d_ws, size_t ws_size,
                              hipStream_t stream) {
    const float* cc    = (const float*)d_in[0];
    const float* memc  = (const float*)d_in[1];
    const float* Wqkv  = (const float*)d_in[2];
    const float* bqkv  = (const float*)d_in[3];
    const float* g_qkv = (const float*)d_in[4];
    const float* b_qkv = (const float*)d_in[5];
    const float* g_mem = (const float*)d_in[6];
    const float* b_mem = (const float*)d_in[7];
    const float* W1    = (const float*)d_in[8];
    const float* b1    = (const float*)d_in[9];
    const float* W2    = (const float*)d_in[10];
    const float* b2    = (const float*)d_in[11];
    const float* Ws1   = (const float*)d_in[12];
    const float* bs1   = (const float*)d_in[13];
    const float* Ws2   = (const float*)d_in[14];
    const float* bs2   = (const float*)d_in[15];
    float* out = (float*)d_out;

    // ws layout (floats). tau region is reused for qkv + h after top-k.
    float* ws   = (float*)d_ws;
    float* tau  = ws;
    float* qkv  = ws;
    float* h    = ws + 10485760;
    float* mems = ws + 25600000;
    float* Ab   = ws + 33988608;
    float* Bb   = mems;

    constexpr int NT      = (NMEM + 63) / 64;      // 1563
    constexpr int NROWS   = BATCH * KTOP;          // 16384
    constexpr int LN_GRID = NROWS / 4;             // 4096

    tau_gemm<<<NT * 4, 256, 0, stream>>>(cc, memc, tau);
    topk_gather<<<BATCH, 256, 0, stream>>>(tau, memc, mems);

    // qkv = LN(mems @ Wqkv + bqkv) * g_qkv + b_qkv
    gemm_rows16<<<BATCH * 4, 256, 0, stream>>>(mems, Wqkv, bqkv, qkv, TOT, 0);
    res_ln<<<LN_GRID, 256, 0, stream>>>(qkv, nullptr, g_qkv, b_qkv, qkv, TOT, NROWS);

    attn<<<BATCH, 256, 0, stream>>>(qkv, Ab);

    // mem1 = LN(mems + attended)
    res_ln<<<LN_GRID, 256, 0, stream>>>(Ab, mems, g_mem, b_mem, Ab, DDIM, NROWS);

    // block 1: mem2 = LN(mlp(mem1) + mem1)
    gemm_rows16<<<BATCH * 4, 256, 0, stream>>>(Ab, W1, b1, h, DDIM, 1);
    gemm_rows16<<<BATCH * 4, 256, 0, stream>>>(h, W2, b2, Bb, DDIM, 0);
    res_ln<<<LN_GRID, 256, 0, stream>>>(Bb, Ab, g_mem, b_mem, Bb, DDIM, NROWS);

    // block 2: mem3 = LN(mlp(mem2) + mem2)
    gemm_rows16<<<BATCH * 4, 256, 0, stream>>>(Bb, W1, b1, h, DDIM, 1);
    gemm_rows16<<<BATCH * 4, 256, 0, stream>>>(h, W2, b2, Ab, DDIM, 0);
    res_ln<<<LN_GRID, 256, 0, stream>>>(Ab, Bb, g_mem, b_mem, Ab, DDIM, NROWS);

    // head: out = relu(mem3 @ Ws1 + bs1) @ Ws2 + bs2
    gemm_rows16<<<BATCH * 4, 256, 0, stream>>>(Ab, Ws1, bs1, h, DDIM, 1);
    gemm_rows16<<<BATCH * 4, 256, 0, stream>>>(h, Ws2, bs2, out, CDIM, 0);
}

// Round 3
// 2484.063 us; speedup vs baseline: 1.1947x; 1.1947x over previous
//
#include <hip/hip_runtime.h>
#include <math.h>

// Problem constants (fixed by reference)
constexpr int BATCH = 256;
constexpr int NMEM  = 100000;
constexpr int CDIM  = 511;
constexpr int DDIM  = 512;
constexpr int TOT   = 640;   // 2*64 + 512
constexpr int KTOP  = 64;
constexpr int KPAD  = 512;   // bf16 K padding for tau GEMM

typedef __attribute__((ext_vector_type(8))) short short8;
typedef __attribute__((ext_vector_type(4))) float floatx4;

__device__ __forceinline__ unsigned short rtn_bf16(float x) {
    unsigned u = __float_as_uint(x);
    u += 0x7FFFu + ((u >> 16) & 1);
    return (unsigned short)(u >> 16);
}

__device__ __forceinline__ void async_ld16(void* lds, const void* g) {
    __builtin_amdgcn_global_load_lds(
        (const __attribute__((address_space(1))) void*)g,
        (__attribute__((address_space(3))) void*)lds, 16, 0, 0);
}

// ---------------------------------------------------------------------------
// K0: fp32 -> bf16 (RTN), pad K 511 -> 512 with zeros. dst[n][512].
// ---------------------------------------------------------------------------
__global__ __launch_bounds__(256) void cvt_bf16_pad(const float* __restrict__ src,
                                                    unsigned short* __restrict__ dst,
                                                    int nrows) {
    size_t total = (size_t)nrows * KPAD;
    for (size_t idx = (size_t)blockIdx.x * 256 + threadIdx.x; idx < total;
         idx += (size_t)gridDim.x * 256) {
        int   k = (int)(idx & (KPAD - 1));
        size_t n = idx >> 9;
        float v = (k < CDIM) ? src[n * CDIM + k] : 0.f;
        dst[idx] = rtn_bf16(v);
    }
}

// ---------------------------------------------------------------------------
// K1: tau16[m][n] = bf16( A2[m,:] . B2[n,:] )  via MFMA 16x16x32 bf16.
// 128x128 tile, BK=64, global_load_lds width=16, XOR-swizzled LDS k-groups.
// Screening-only accuracy (sigma ~0.03 << radix bin width ~9).
// ---------------------------------------------------------------------------
__global__ __launch_bounds__(256) void tau_gemm_bf16(const unsigned short* __restrict__ A2,
                                                     const unsigned short* __restrict__ B2,
                                                     unsigned short* __restrict__ tau16) {
    __shared__ unsigned short As[128 * 64];
    __shared__ unsigned short Bs[128 * 64];
    int bx = blockIdx.x;
    int mt = bx & 1, nt = bx >> 1;
    int m0 = mt * 128, n0 = nt * 128;
    int t = threadIdx.x;
    int wave = t >> 6, lane = t & 63;
    int rh = wave >> 1, chf = wave & 1;     // wave row-half / col-half
    int l15 = lane & 15, quad = lane >> 4;

    floatx4 acc[4][4];
    floatx4 zero = {0.f, 0.f, 0.f, 0.f};
#pragma unroll
    for (int i = 0; i < 4; i++)
#pragma unroll
        for (int j = 0; j < 4; j++) acc[i][j] = zero;

    // staging source mapping (swizzle: LDS slot s of row r holds kgroup s^(r&7))
    int srow = t >> 3;                    // 0..31 (+32*i)
    int skg  = (t & 7) ^ (srow & 7);      // source k-group for this lane's slot

    for (int c = 0; c < 8; c++) {
        int k0 = c * 64;
        __syncthreads();
#pragma unroll
        for (int i = 0; i < 4; i++) {
            int rowA = i * 32 + srow;
            const unsigned short* ga = A2 + (size_t)(m0 + rowA) * KPAD + k0 + skg * 8;
            async_ld16((void*)(As + i * 2048 + wave * 512), (const void*)ga);
            int rowB = n0 + i * 32 + srow;
            if (rowB > NMEM - 1) rowB = NMEM - 1;
            const unsigned short* gb = B2 + (size_t)rowB * KPAD + k0 + skg * 8;
            async_ld16((void*)(Bs + i * 2048 + wave * 512), (const void*)gb);
        }
        __syncthreads();
#pragma unroll
        for (int s = 0; s < 2; s++) {
            int g = s * 4 + quad;
            short8 af[4], bf[4];
#pragma unroll
            for (int mi = 0; mi < 4; mi++) {
                int row = rh * 64 + mi * 16 + l15;
                af[mi] = *(const short8*)&As[row * 64 + ((g ^ (row & 7)) << 3)];
            }
#pragma unroll
            for (int ni = 0; ni < 4; ni++) {
                int col = chf * 64 + ni * 16 + l15;
                bf[ni] = *(const short8*)&Bs[col * 64 + ((g ^ (col & 7)) << 3)];
            }
#pragma unroll
            for (int mi = 0; mi < 4; mi++)
#pragma unroll
                for (int ni = 0; ni < 4; ni++)
                    acc[mi][ni] = __builtin_amdgcn_mfma_f32_16x16x32_bf16(
                        af[mi], bf[ni], acc[mi][ni], 0, 0, 0);
        }
    }
    // epilogue: C frag row = quad*4+reg, col = lane&15
#pragma unroll
    for (int mi = 0; mi < 4; mi++) {
#pragma unroll
        for (int ni = 0; ni < 4; ni++) {
            int n = n0 + chf * 64 + ni * 16 + l15;
            if (n < NMEM) {
#pragma unroll
                for (int r = 0; r < 4; r++) {
                    int m = m0 + rh * 64 + mi * 16 + quad * 4 + r;
                    tau16[(size_t)m * NMEM + n] = rtn_bf16(acc[mi][ni][r]);
                }
            }
        }
    }
}

// ---------------------------------------------------------------------------
// K2: per-row top-64. Radix histogram on bf16 tau (12-bit bins) with cut-1
// safety margin -> candidates -> EXACT fp32 recompute of candidate dots ->
// 64x single-wave argmax (value desc, index asc) -> fused gather.
// ---------------------------------------------------------------------------
constexpr int CAND_CAP = 4096;
constexpr int NBINS    = 4096;

__device__ __forceinline__ unsigned mono16(unsigned x) {
    return (x ^ ((x & 0x8000u) ? 0xFFFFu : 0x8000u)) & 0xFFFFu;
}

__global__ __launch_bounds__(256) void topk_gather(const unsigned short* __restrict__ tau16,
                                                   const float* __restrict__ cc,
                                                   const float* __restrict__ memc,
                                                   float* __restrict__ mems) {
    int row = blockIdx.x;
    const unsigned* tr32 = (const unsigned*)(tau16 + (size_t)row * NMEM);
    __shared__ int   hist[NBINS];
    __shared__ int   segsum[256];
    __shared__ int   cnt;
    __shared__ int   cut_s;
    __shared__ float cv[CAND_CAP];
    __shared__ int   ci[CAND_CAP];
    __shared__ int   sel[KTOP];
    int t = threadIdx.x;

    for (int i = t; i < NBINS; i += 256) hist[i] = 0;
    if (t == 0) cnt = 0;
    __syncthreads();

    for (int i = t; i < NMEM / 2; i += 256) {
        unsigned u = tr32[i];
        atomicAdd(&hist[mono16(u & 0xFFFFu) >> 4], 1);
        atomicAdd(&hist[mono16(u >> 16) >> 4], 1);
    }
    __syncthreads();

    {   // segment sums (16 bins per thread)
        int s = 0, base = t * 16;
#pragma unroll
        for (int i = 0; i < 16; i++) s += hist[base + i];
        segsum[t] = s;
    }
    __syncthreads();
    if (t == 0) {
        int acc = 0, cut = 0;
        for (int s = 255; s >= 0; s--) {
            if (acc + segsum[s] >= KTOP) {
                int base = s * 16;
                for (int bb = 15; bb >= 0; bb--) {
                    acc += hist[base + bb];
                    if (acc >= KTOP) { cut = base + bb; break; }
                }
                break;
            }
            acc += segsum[s];
        }
        cut_s = (cut > 0) ? cut - 1 : 0;   // one-bin safety margin
    }
    __syncthreads();
    unsigned cut = (unsigned)cut_s;
    for (int i = t; i < NMEM / 2; i += 256) {
        unsigned u = tr32[i];
        if ((mono16(u & 0xFFFFu) >> 4) >= cut) {
            int p = atomicAdd(&cnt, 1);
            if (p < CAND_CAP) ci[p] = 2 * i;
        }
        if ((mono16(u >> 16) >> 4) >= cut) {
            int p = atomicAdd(&cnt, 1);
            if (p < CAND_CAP) ci[p] = 2 * i + 1;
        }
    }
    __syncthreads();
    int m = cnt < CAND_CAP ? cnt : CAND_CAP;

    // exact fp32 recompute of candidate dots (boundary decisions are exact)
    {
        const float* cr = cc + (size_t)row * CDIM;
        for (int p = t; p < m; p += 256) {
            const float* mr = memc + (size_t)ci[p] * CDIM;
            float s = 0.f;
#pragma unroll 4
            for (int k = 0; k < CDIM; k++) s = fmaf(cr[k], mr[k], s);
            cv[p] = s;
        }
    }
    __syncthreads();

    if (t < 64) {
        // single-wave extraction: shuffle butterfly w/ (desc value, asc index)
        for (int j = 0; j < KTOP; j++) {
            float bv = -INFINITY;
            int   bi = 0x7FFFFFFF, bp = -1;
            for (int p = t; p < m; p += 64) {
                float v = cv[p]; int ii = ci[p];
                if (v > bv || (v == bv && ii < bi)) { bv = v; bi = ii; bp = p; }
            }
            float wv = bv; int wi = bi;
#pragma unroll
            for (int o = 1; o < 64; o <<= 1) {
                float ov = __shfl_xor(wv, o, 64);
                int   oi = __shfl_xor(wi, o, 64);
                if (ov > wv || (ov == wv && oi < wi)) { wv = ov; wi = oi; }
            }
            if (t == 0) {
                sel[j] = wi;
                mems[((size_t)row * KTOP + j) * DDIM] = wv;   // exact delta
            }
            if (bp >= 0 && bi == wi) cv[bp] = -INFINITY;      // owner clears
        }
    }
    __syncthreads();
    // gather memc rows
    for (int j = 0; j < KTOP; j++) {
        int src = sel[j];
        for (int col = t; col < CDIM; col += 256)
            mems[((size_t)row * KTOP + j) * DDIM + 1 + col] = memc[(size_t)src * CDIM + col];
    }
}

// ---------------------------------------------------------------------------
// K3: batched GEMM  Y[b] (16 rows) = X[b](16x512) @ W(512xNo) + bias [opt relu]
// ---------------------------------------------------------------------------
__global__ __launch_bounds__(256) void gemm_rows16(const float* __restrict__ X,
                                                   const float* __restrict__ W,
                                                   const float* __restrict__ bias,
                                                   float* __restrict__ Y,
                                                   int No, int do_relu) {
    int bx = blockIdx.x;
    int b  = bx >> 2;
    int r0 = (bx & 3) * 16;
    const float* Xb = X + ((size_t)b * 64 + r0) * DDIM;
    float*       Yb = Y + ((size_t)b * 64 + r0) * (size_t)No;
    int t = threadIdx.x;

    for (int c0 = t; c0 < No; c0 += 256) {
        float acc[16];
#pragma unroll
        for (int i = 0; i < 16; i++) acc[i] = 0.f;
        const float* Wc = W + c0;
        for (int k = 0; k < DDIM; k += 4) {
            float w0 = Wc[(size_t)(k + 0) * No];
            float w1 = Wc[(size_t)(k + 1) * No];
            float w2 = Wc[(size_t)(k + 2) * No];
            float w3 = Wc[(size_t)(k + 3) * No];
#pragma unroll
            for (int i = 0; i < 16; i++) {
                float4 x4 = *(const float4*)(Xb + i * DDIM + k);
                acc[i] = fmaf(x4.w, w3, fmaf(x4.z, w2, fmaf(x4.y, w1, fmaf(x4.x, w0, acc[i]))));
            }
        }
        float bb = bias[c0];
#pragma unroll
        for (int i = 0; i < 16; i++) {
            float v = acc[i] + bb;
            if (do_relu) v = fmaxf(v, 0.f);
            Yb[(size_t)i * No + c0] = v;
        }
    }
}

// ---------------------------------------------------------------------------
// K4: attention per batch.
// ---------------------------------------------------------------------------
__global__ __launch_bounds__(256) void attn(const float* __restrict__ qkv,
                                            float* __restrict__ att) {
    __shared__ float smem[64 * 65 * 2];   // qs | ks, later reused as vs
    __shared__ float wsm[64][64];
    float (*qs)[65]  = (float(*)[65])smem;
    float (*ks)[65]  = (float(*)[65])(smem + 64 * 65);
    float (*vs)[128] = (float(*)[128])smem;

    int b = blockIdx.x, t = threadIdx.x;
    const float* Qb = qkv + (size_t)b * 64 * TOT;

    for (int idx = t; idx < 64 * 64; idx += 256) {
        int i = idx >> 6, d = idx & 63;
        qs[i][d] = Qb[(size_t)i * TOT + d];
        ks[i][d] = Qb[(size_t)i * TOT + 64 + d];
    }
    __syncthreads();
    {
        int i  = t >> 2;
        int jb = (t & 3) * 16;
#pragma unroll
        for (int jj = 0; jj < 16; jj++) {
            int j = jb + jj;
            float s = 0.f;
#pragma unroll 8
            for (int d = 0; d < 64; d++) s = fmaf(qs[i][d], ks[j][d], s);
            wsm[i][j] = s * 0.125f;   // 64^{-1/2}
        }
    }
    __syncthreads();
    if (t < 64) {
        float mx = -INFINITY;
        for (int j = 0; j < 64; j++) mx = fmaxf(mx, wsm[t][j]);
        float sum = 0.f;
        for (int j = 0; j < 64; j++) { float e = expf(wsm[t][j] - mx); wsm[t][j] = e; sum += e; }
        float inv = 1.f / sum;
        for (int j = 0; j < 64; j++) wsm[t][j] *= inv;
    }
    __syncthreads();
    for (int ch = 0; ch < 4; ch++) {
        for (int idx = t; idx < 64 * 128; idx += 256) {
            int j = idx >> 7, d = idx & 127;
            vs[j][d] = Qb[(size_t)j * TOT + 128 + ch * 128 + d];
        }
        __syncthreads();
        int d  = t & 127;
        int i0 = (t >> 7) * 32;
        for (int i = i0; i < i0 + 32; i++) {
            float s = 0.f;
#pragma unroll 8
            for (int j = 0; j < 64; j++) s = fmaf(wsm[i][j], vs[j][d], s);
            att[((size_t)b * 64 + i) * DDIM + ch * 128 + d] = s;
        }
        __syncthreads();
    }
}

// ---------------------------------------------------------------------------
// K5: Y[row] = LN(X[row] (+ Res[row])) * g + b    one wave per row.
// ---------------------------------------------------------------------------
__global__ __launch_bounds__(256) void res_ln(const float* __restrict__ X,
                                              const float* __restrict__ Res,
                                              const float* __restrict__ g,
                                              const float* __restrict__ bta,
                                              float* __restrict__ Y,
                                              int width, int nrows) {
    int wave = threadIdx.x >> 6;
    int lane = threadIdx.x & 63;
    int row  = blockIdx.x * 4 + wave;
    if (row >= nrows) return;
    const float* xr = X + (size_t)row * width;
    const float* rr = Res ? Res + (size_t)row * width : nullptr;
    float vals[12];
    int per = width >> 6;   // 8 (512) or 10 (640)
    float sum = 0.f, ssq = 0.f;
    for (int e = 0; e < per; e++) {
        int col = lane + e * 64;
        float v = xr[col];
        if (rr) v += rr[col];
        vals[e] = v; sum += v; ssq = fmaf(v, v, ssq);
    }
    for (int o = 32; o > 0; o >>= 1) {
        sum += __shfl_down(sum, o, 64);
        ssq += __shfl_down(ssq, o, 64);
    }
    sum = __shfl(sum, 0, 64);
    ssq = __shfl(ssq, 0, 64);
    float mu  = sum / width;
    float var = ssq / width - mu * mu;
    float rs  = rsqrtf(var + 1e-5f);
    float* yr = Y + (size_t)row * width;
    for (int e = 0; e < per; e++) {
        int col = lane + e * 64;
        yr[col] = (vals[e] - mu) * rs * g[col] + bta[col];
    }
}

// ---------------------------------------------------------------------------
extern "C" void kernel_launch(void* const* d_in, const int* in_sizes, int n_in,
                              void* d_out, int out_size, void* d_ws, size_t ws_size,
                              hipStream_t stream) {
    const float* cc    = (const float*)d_in[0];
    const float* memc  = (const float*)d_in[1];
    const float* Wqkv  = (const float*)d_in[2];
    const float* bqkv  = (const float*)d_in[3];
    const float* g_qkv = (const float*)d_in[4];
    const float* b_qkv = (const float*)d_in[5];
    const float* g_mem = (const float*)d_in[6];
    const float* b_mem = (const float*)d_in[7];
    const float* W1    = (const float*)d_in[8];
    const float* b1    = (const float*)d_in[9];
    const float* W2    = (const float*)d_in[10];
    const float* b2    = (const float*)d_in[11];
    const float* Ws1   = (const float*)d_in[12];
    const float* bs1   = (const float*)d_in[13];
    const float* Ws2   = (const float*)d_in[14];
    const float* bs2   = (const float*)d_in[15];
    float* out = (float*)d_out;

    // ws layout (float units), peak 38.47e6 floats = 153.9 MB:
    //   phase 1 (tau):  B2 bf16 [0, 25.6e6) | tau16 [25.6e6, 38.4e6) | A2 [38.4e6,+65536/2)
    //   phase 2:        mems [0, 8.39e6) | qkv [8.39e6,18.87e6) | h [18.87e6,27.26e6)
    //                   Ab [27.26e6,35.65e6) | Bb = mems   (tau16/B2 dead by then)
    float* ws = (float*)d_ws;
    unsigned short* B2    = (unsigned short*)ws;
    unsigned short* tau16 = (unsigned short*)(ws + 25600000);
    unsigned short* A2    = (unsigned short*)(ws + 38400000);
    float* mems = ws;
    float* qkv  = ws + 8388608;
    float* h    = ws + 18874368;
    float* Ab   = ws + 27262976;
    float* Bb   = mems;

    constexpr int NROWS   = BATCH * KTOP;          // 16384
    constexpr int LN_GRID = NROWS / 4;             // 4096
    constexpr int NTILES  = (NMEM + 127) / 128;    // 782

    cvt_bf16_pad<<<2048, 256, 0, stream>>>(memc, B2, NMEM);
    cvt_bf16_pad<<<64, 256, 0, stream>>>(cc, A2, BATCH);
    tau_gemm_bf16<<<NTILES * 2, 256, 0, stream>>>(A2, B2, tau16);
    topk_gather<<<BATCH, 256, 0, stream>>>(tau16, cc, memc, mems);

    // qkv = LN(mems @ Wqkv + bqkv) * g_qkv + b_qkv
    gemm_rows16<<<BATCH * 4, 256, 0, stream>>>(mems, Wqkv, bqkv, qkv, TOT, 0);
    res_ln<<<LN_GRID, 256, 0, stream>>>(qkv, nullptr, g_qkv, b_qkv, qkv, TOT, NROWS);

    attn<<<BATCH, 256, 0, stream>>>(qkv, Ab);

    // mem1 = LN(mems + attended)
    res_ln<<<LN_GRID, 256, 0, stream>>>(Ab, mems, g_mem, b_mem, Ab, DDIM, NROWS);

    // block 1: mem2 = LN(mlp(mem1) + mem1)
    gemm_rows16<<<BATCH * 4, 256, 0, stream>>>(Ab, W1, b1, h, DDIM, 1);
    gemm_rows16<<<BATCH * 4, 256, 0, stream>>>(h, W2, b2, Bb, DDIM, 0);
    res_ln<<<LN_GRID, 256, 0, stream>>>(Bb, Ab, g_mem, b_mem, Bb, DDIM, NROWS);

    // block 2: mem3 = LN(mlp(mem2) + mem2)
    gemm_rows16<<<BATCH * 4, 256, 0, stream>>>(Bb, W1, b1, h, DDIM, 1);
    gemm_rows16<<<BATCH * 4, 256, 0, stream>>>(h, W2, b2, Ab, DDIM, 0);
    res_ln<<<LN_GRID, 256, 0, stream>>>(Ab, Bb, g_mem, b_mem, Ab, DDIM, NROWS);

    // head: out = relu(mem3 @ Ws1 + bs1) @ Ws2 + bs2
    gemm_rows16<<<BATCH * 4, 256, 0, stream>>>(Ab, Ws1, bs1, h, DDIM, 1);
    gemm_rows16<<<BATCH * 4, 256, 0, stream>>>(h, Ws2, bs2, out, CDIM, 0);
}